// Round 8
// baseline (319.840 us; speedup 1.0000x reference)
//
#include <hip/hip_runtime.h>
#include <hip/hip_bf16.h>

// Single-head causal attention with value-residual mix.
// B=16, T=2048, C=768, H=64. Inputs/outputs f32; internal compute bf16 MFMA.
// Outputs (concat flat, f32): y=[B,T,64], then v1=[B,T,64].

constexpr int BATCH = 16;
constexpr int TSEQ  = 2048;
constexpr int CEMB  = 768;
constexpr int HS    = 64;
constexpr size_t NTOK    = (size_t)BATCH * TSEQ;  // 32768
constexpr size_t OUTHALF = NTOK * HS;             // 2,097,152 elements

typedef __bf16 bf16x4 __attribute__((ext_vector_type(4)));
typedef __bf16 bf16x8 __attribute__((ext_vector_type(8)));
typedef float  f32x4  __attribute__((ext_vector_type(4)));
typedef short  s16x4  __attribute__((ext_vector_type(4)));

union B4S4 { bf16x4 h; s16x4 s; };

// ---------------------------------------------------------------------------
// Kernel 0: transpose weights to bf16.
// blocks 0..35: WT[m][h][c] = Wm[c][h];  block 36: WprojT[h'][h]
// ---------------------------------------------------------------------------
__global__ __launch_bounds__(256) void prep_kernel(
    const float* __restrict__ wk, const float* __restrict__ wq,
    const float* __restrict__ wv, const float* __restrict__ wproj,
    __bf16* __restrict__ wt, __bf16* __restrict__ wpt)
{
    __shared__ __bf16 t[64][66];
    const int bid = blockIdx.x;
    if (bid < 36) {
        const int m = bid / 12, c0 = (bid % 12) * 64;
        const float* src = (m == 0) ? wk : (m == 1) ? wq : wv;
        for (int i = threadIdx.x; i < 4096; i += 256) {
            const int c = i >> 6, h = i & 63;
            t[c][h] = (__bf16)src[(size_t)(c0 + c) * HS + h];
        }
        __syncthreads();
        for (int i = threadIdx.x; i < 4096; i += 256) {
            const int h = i >> 6, c = i & 63;
            wt[(size_t)m * HS * CEMB + (size_t)h * CEMB + c0 + c] = t[c][h];
        }
    } else {
        for (int i = threadIdx.x; i < 4096; i += 256) {
            const int h = i >> 6, hp = i & 63;
            t[h][hp] = (__bf16)wproj[i];
        }
        __syncthreads();
        for (int i = threadIdx.x; i < 4096; i += 256) {
            const int hp = i >> 6, h = i & 63;
            wpt[i] = t[h][hp];
        }
    }
}

// ---------------------------------------------------------------------------
// Kernel 1: QKV projection (round-7 structure, unchanged).
// ---------------------------------------------------------------------------
__global__ __launch_bounds__(256, 2) void qkv_kernel(
    const float* __restrict__ x,      // [B*T, 768]
    const float* __restrict__ v1,     // [B*T, 64]
    const __bf16* __restrict__ wt,    // [3][64][768]
    const float* __restrict__ lamb_p,
    __bf16* __restrict__ kk,          // [B*T, 64]
    __bf16* __restrict__ qq,          // [B*T, 64]
    __bf16* __restrict__ vt)          // [B][64][2048]
{
    __shared__ __bf16 xl[2][64][88];

    const int wave = threadIdx.x >> 6;
    const int lane = threadIdx.x & 63;
    const int l16  = lane & 15;
    const int quad = lane >> 4;
    const size_t row0 = (size_t)blockIdx.x * 64;

    const int tok_s = threadIdx.x >> 2;
    const int cq    = threadIdx.x & 3;
    const float* xsrc = x + (row0 + tok_s) * CEMB + cq * 16;

    const __bf16* wbase[3];
    #pragma unroll
    for (int m = 0; m < 3; ++m)
        wbase[m] = wt + ((size_t)m * HS + wave * 16 + l16) * CEMB + quad * 8;

    f32x4 acc[3][4];
    #pragma unroll
    for (int m = 0; m < 3; ++m)
        #pragma unroll
        for (int rt = 0; rt < 4; ++rt)
            acc[m][rt] = (f32x4){0.f, 0.f, 0.f, 0.f};

    {
        f32x4 t0 = *(const f32x4*)(xsrc);
        f32x4 t1 = *(const f32x4*)(xsrc + 4);
        f32x4 t2 = *(const f32x4*)(xsrc + 8);
        f32x4 t3 = *(const f32x4*)(xsrc + 12);
        bf16x8 lo, hi;
        #pragma unroll
        for (int i = 0; i < 4; ++i) {
            lo[i] = (__bf16)t0[i]; lo[i + 4] = (__bf16)t1[i];
            hi[i] = (__bf16)t2[i]; hi[i + 4] = (__bf16)t3[i];
        }
        *(bf16x8*)&xl[0][tok_s][cq * 16]     = lo;
        *(bf16x8*)&xl[0][tok_s][cq * 16 + 8] = hi;
    }
    bf16x8 wc[3][2];
    #pragma unroll
    for (int m = 0; m < 3; ++m)
        #pragma unroll
        for (int ks = 0; ks < 2; ++ks)
            wc[m][ks] = *(const bf16x8*)(wbase[m] + ks * 32);
    __syncthreads();

    for (int c0 = 0; c0 < CEMB; c0 += 64) {
        const int buf = (c0 >> 6) & 1;
        const bool notlast = (c0 + 64 < CEMB);

        f32x4 nx0, nx1, nx2, nx3;
        bf16x8 wn[3][2];
        if (notlast) {
            const float* xs = xsrc + c0 + 64;
            nx0 = *(const f32x4*)(xs);
            nx1 = *(const f32x4*)(xs + 4);
            nx2 = *(const f32x4*)(xs + 8);
            nx3 = *(const f32x4*)(xs + 12);
            #pragma unroll
            for (int m = 0; m < 3; ++m)
                #pragma unroll
                for (int ks = 0; ks < 2; ++ks)
                    wn[m][ks] = *(const bf16x8*)(wbase[m] + c0 + 64 + ks * 32);
        }

        #pragma unroll
        for (int ks = 0; ks < 2; ++ks) {
            bf16x8 a[4];
            #pragma unroll
            for (int rt = 0; rt < 4; ++rt)
                a[rt] = *(const bf16x8*)&xl[buf][rt * 16 + l16][ks * 32 + quad * 8];
            #pragma unroll
            for (int m = 0; m < 3; ++m)
                #pragma unroll
                for (int rt = 0; rt < 4; ++rt)
                    acc[m][rt] = __builtin_amdgcn_mfma_f32_16x16x32_bf16(
                        a[rt], wc[m][ks], acc[m][rt], 0, 0, 0);
        }

        if (notlast) {
            bf16x8 lo, hi;
            #pragma unroll
            for (int i = 0; i < 4; ++i) {
                lo[i] = (__bf16)nx0[i]; lo[i + 4] = (__bf16)nx1[i];
                hi[i] = (__bf16)nx2[i]; hi[i + 4] = (__bf16)nx3[i];
            }
            *(bf16x8*)&xl[buf ^ 1][tok_s][cq * 16]     = lo;
            *(bf16x8*)&xl[buf ^ 1][tok_s][cq * 16 + 8] = hi;
            #pragma unroll
            for (int m = 0; m < 3; ++m)
                #pragma unroll
                for (int ks = 0; ks < 2; ++ks)
                    wc[m][ks] = wn[m][ks];
            __syncthreads();
        }
    }

    const float lam = lamb_p[0];
    const int col = wave * 16 + l16;
    const int b  = (int)(row0 >> 11);
    __bf16* vtb = vt + (size_t)b * HS * TSEQ + (size_t)col * TSEQ;
    #pragma unroll
    for (int rt = 0; rt < 4; ++rt) {
        const size_t tok0 = row0 + rt * 16 + quad * 4;
        bf16x4 pk;
        #pragma unroll
        for (int r = 0; r < 4; ++r) {
            const size_t idx = (tok0 + r) * HS + col;
            kk[idx] = (__bf16)acc[0][rt][r];
            qq[idx] = (__bf16)acc[1][rt][r];
            pk[r] = (__bf16)((1.0f - lam) * acc[2][rt][r] + lam * v1[idx]);
        }
        *(bf16x4*)(vtb + (tok0 & 2047)) = pk;
    }
}

// ---------------------------------------------------------------------------
// Kernel 2: flash attention, S^T formulation (register-resident P).
// Grid: B*128 blocks (one 16-row q-tile each); 4 waves split the s-tiles.
// S^T = K Q^T (operand swap): C-layout row = s (quad*4+r), col = t (l16).
// P (=exp(S^T)) in that layout IS the A-frag layout of mfma_16x16x16 =>
// PV runs from registers; V^T b64 loads are B-frags. Fixed-scale softmax
// (no running max; normalization cancels the common scale exactly).
// Merge = pure adds across waves; wave0 projects.
// ---------------------------------------------------------------------------
__global__ __launch_bounds__(256, 2) void attn_kernel(
    const __bf16* __restrict__ q,     // [B*T, 64]
    const __bf16* __restrict__ k,     // [B*T, 64]
    const __bf16* __restrict__ vt,    // [B][64][2048]
    const __bf16* __restrict__ wpt,   // [64][64] = Wproj^T
    const float* __restrict__ bproj,  // [64]
    float* __restrict__ y)            // [B*T, 64] f32
{
    __shared__ float  olds[4][16][64];   // per-wave unnormalized O
    __shared__ float  lb[4][16];         // per-wave row sums
    __shared__ __bf16 plds[16][72];      // merged O for projection A-frags

    const int b    = blockIdx.x >> 7;
    const int j    = blockIdx.x & 127;   // q-tile: rows [16j, 16j+16)
    const int wave = threadIdx.x >> 6;
    const int lane = threadIdx.x & 63;
    const int l16  = lane & 15;
    const int quad = lane >> 4;

    const size_t tokbase = (size_t)b * TSEQ + j * 16;
    const __bf16* qbase = q + (tokbase + l16) * HS + quad * 8;
    bf16x8 qf0 = *(const bf16x8*)(qbase);          // Q[t=l16][h=quad*8+j]
    bf16x8 qf1 = *(const bf16x8*)(qbase + 32);
    const __bf16* kb  = k  + (size_t)b * TSEQ * HS;
    const __bf16* vtb = vt + (size_t)b * HS * TSEQ;

    f32x4 o_acc[4];
    #pragma unroll
    for (int ht = 0; ht < 4; ++ht) o_acc[ht] = (f32x4){0.f, 0.f, 0.f, 0.f};
    float rs = 0.f;

    const float scale = 0.125f;          // 1/sqrt(64), natural-exp domain
    const int tdiag = j >> 2;
    const int trow  = j * 16 + l16;      // this lane's q-row (t = l16)

    for (int t = wave; t <= tdiag; t += 4) {
        const int s0 = t * 64;

        // S^T tiles: D = K_frag * Q_frag (A=K, B=Q). 4 s-subtiles of 16.
        f32x4 st4[4];
        #pragma unroll
        for (int stt = 0; stt < 4; ++stt) {
            const __bf16* kbp = kb + (size_t)(s0 + stt * 16 + l16) * HS + quad * 8;
            bf16x8 kf0 = *(const bf16x8*)(kbp);
            bf16x8 kf1 = *(const bf16x8*)(kbp + 32);
            f32x4 c = (f32x4){0.f, 0.f, 0.f, 0.f};
            c = __builtin_amdgcn_mfma_f32_16x16x32_bf16(kf0, qf0, c, 0, 0, 0);
            c = __builtin_amdgcn_mfma_f32_16x16x32_bf16(kf1, qf1, c, 0, 0, 0);
            st4[stt] = c;
        }

        // Hoist V^T B-frags (b64 each): V[s=s0+kc*16+quad*4+jj][h=ht*16+l16]
        B4S4 vb[4][4];
        #pragma unroll
        for (int ht = 0; ht < 4; ++ht)
            #pragma unroll
            for (int kc = 0; kc < 4; ++kc)
                vb[ht][kc].h = *(const bf16x4*)(vtb
                    + (size_t)(ht * 16 + l16) * TSEQ + s0 + kc * 16 + quad * 4);

        // p = exp(s*scale), masked to 0 above the diagonal; accumulate row sum.
        const bool isdiag = (t == tdiag);
        B4S4 pa[4];
        #pragma unroll
        for (int stt = 0; stt < 4; ++stt) {
            const int sbase = s0 + stt * 16 + quad * 4;
            bf16x4 ph;
            #pragma unroll
            for (int r = 0; r < 4; ++r) {
                float p = __expf(st4[stt][r] * scale);
                if (isdiag && (sbase + r > trow)) p = 0.f;
                rs += p;
                ph[r] = (__bf16)p;
            }
            pa[stt].h = ph;
        }

        // O += P V via 16x16x16 (A = P from regs, B = V^T frags).
        #pragma unroll
        for (int ht = 0; ht < 4; ++ht)
            #pragma unroll
            for (int kc = 0; kc < 4; ++kc)
                o_acc[ht] = __builtin_amdgcn_mfma_f32_16x16x16bf16_1k(
                    pa[kc].s, vb[ht][kc].s, o_acc[ht], 0, 0, 0);
    }

    // Row-sum across quads (t = l16 fixed): lanes l16, l16+16, +32, +48.
    rs += __shfl_xor(rs, 16);
    rs += __shfl_xor(rs, 32);

    // Deposit per-wave partials (shared scale => merge is pure adds).
    #pragma unroll
    for (int ht = 0; ht < 4; ++ht)
        #pragma unroll
        for (int r = 0; r < 4; ++r)
            olds[wave][quad * 4 + r][ht * 16 + l16] = o_acc[ht][r];
    if (lane < 16) lb[wave][lane] = rs;
    __syncthreads();

    if (wave == 0) {
        float linv[4];
        #pragma unroll
        for (int r = 0; r < 4; ++r) {
            const int rw = quad * 4 + r;
            const float ls = lb[0][rw] + lb[1][rw] + lb[2][rw] + lb[3][rw];
            linv[r] = 1.0f / ls;
        }
        #pragma unroll
        for (int ht = 0; ht < 4; ++ht)
            #pragma unroll
            for (int r = 0; r < 4; ++r) {
                const int rw = quad * 4 + r, cc = ht * 16 + l16;
                const float o = olds[0][rw][cc] + olds[1][rw][cc]
                              + olds[2][rw][cc] + olds[3][rw][cc];
                plds[rw][cc] = (__bf16)(o * linv[r]);
            }

        // y = O @ Wproj + bproj
        f32x4 res[4];
        #pragma unroll
        for (int nt = 0; nt < 4; ++nt) res[nt] = (f32x4){0.f, 0.f, 0.f, 0.f};
        #pragma unroll
        for (int ks = 0; ks < 2; ++ks) {
            bf16x8 of = *(const bf16x8*)&plds[l16][ks * 32 + quad * 8];
            #pragma unroll
            for (int nt = 0; nt < 4; ++nt) {
                bf16x8 wf = *(const bf16x8*)(wpt + (size_t)(nt * 16 + l16) * HS
                                             + ks * 32 + quad * 8);
                res[nt] = __builtin_amdgcn_mfma_f32_16x16x32_bf16(of, wf, res[nt], 0, 0, 0);
            }
        }
        #pragma unroll
        for (int nt = 0; nt < 4; ++nt) {
            const float bp = bproj[nt * 16 + l16];
            #pragma unroll
            for (int r = 0; r < 4; ++r)
                y[(tokbase + quad * 4 + r) * HS + nt * 16 + l16] = res[nt][r] + bp;
        }
    }
}

// ---------------------------------------------------------------------------
// Kernel 3: v1 passthrough f32->f32.
// ---------------------------------------------------------------------------
__global__ __launch_bounds__(256) void copy_kernel(
    const float* __restrict__ src, float* __restrict__ dst)
{
    const size_t i = ((size_t)blockIdx.x * 256 + threadIdx.x) * 4;
    *(f32x4*)(dst + i) = *(const f32x4*)(src + i);
}

extern "C" void kernel_launch(void* const* d_in, const int* in_sizes, int n_in,
                              void* d_out, int out_size, void* d_ws, size_t ws_size,
                              hipStream_t stream) {
    const float* x     = (const float*)d_in[0];
    const float* v1    = (const float*)d_in[1];
    const float* wk    = (const float*)d_in[2];
    const float* wq    = (const float*)d_in[3];
    const float* wv    = (const float*)d_in[4];
    const float* wproj = (const float*)d_in[5];
    const float* bproj = (const float*)d_in[6];
    const float* lamb  = (const float*)d_in[7];

    float* out = (float*)d_out;
    __bf16* kp  = (__bf16*)(out + OUTHALF);   // out1 region as bf16 scratch
    __bf16* vtp = kp + OUTHALF;
    __bf16* qp  = (__bf16*)d_ws;              // ws: q | WT | WprojT
    __bf16* wt  = qp + OUTHALF;
    __bf16* wpt = wt + (size_t)3 * HS * CEMB;

    prep_kernel<<<dim3(37), dim3(256), 0, stream>>>(wk, wq, wv, wproj, wt, wpt);

    qkv_kernel<<<dim3((int)(NTOK / 64)), dim3(256), 0, stream>>>(
        x, v1, wt, lamb, kp, qp, vtp);

    attn_kernel<<<dim3(BATCH * 128), dim3(256), 0, stream>>>(
        qp, kp, vtp, wpt, bproj, out);

    copy_kernel<<<dim3((int)(OUTHALF / (256 * 4))), dim3(256), 0, stream>>>(
        v1, out + OUTHALF);
}